// Round 5
// baseline (293.447 us; speedup 1.0000x reference)
//
#include <hip/hip_runtime.h>

typedef unsigned short u16;
typedef unsigned int u32;
typedef __bf16 bf16x8 __attribute__((ext_vector_type(8)));
typedef float f32x4 __attribute__((ext_vector_type(4)));

#define MFMA16(a, b, c) __builtin_amdgcn_mfma_f32_16x16x32_bf16(a, b, c, 0, 0, 0)
#define LOG2E 1.4426950408889634f

__device__ __forceinline__ u16 f2bf(float f) {
  u32 u = __float_as_uint(f);
  u += 0x7FFFu + ((u >> 16) & 1u);   // RNE to bf16
  return (u16)(u >> 16);
}

__device__ __forceinline__ void gld16(u16* lds, const u16* g) {
  __builtin_amdgcn_global_load_lds((const __attribute__((address_space(1))) void*)g,
                                   (__attribute__((address_space(3))) void*)lds,
                                   16, 0, 0);
}

// Exact integer replication of T5 bucketing (bidirectional, 32 buckets, max_dist 128).
__device__ __forceinline__ int t5_bucket(int rp) {
  int ret = rp > 0 ? 16 : 0;
  int a = rp < 0 ? -rp : rp;
  int b;
  if      (a <  8) b = a;
  else if (a < 12) b = 8;
  else if (a < 16) b = 9;
  else if (a < 23) b = 10;
  else if (a < 32) b = 11;
  else if (a < 46) b = 12;
  else if (a < 64) b = 13;
  else if (a < 91) b = 14;
  else             b = 15;
  return ret + b;
}

// ---------------- fused prep, grid 1024: blocks 0..511 X cvt, 512..1023 W cvt ----
__global__ __launch_bounds__(256) void prep(const float4* __restrict__ X, ushort4* __restrict__ Xb,
                                            const float* __restrict__ w0, const float* __restrict__ w1,
                                            const float* __restrict__ w2, const float* __restrict__ w3,
                                            u16* __restrict__ out) {
  int bid = blockIdx.x;
  if (bid < 512) {
#pragma unroll
    for (int i = 0; i < 8; i++) {
      int g = bid * 2048 + i * 256 + threadIdx.x;
      float4 v = X[g];
      ushort4 o;
      o.x = f2bf(v.x); o.y = f2bf(v.y); o.z = f2bf(v.z); o.w = f2bf(v.w);
      Xb[g] = o;
    }
    return;
  }
  bid -= 512;
  __shared__ __align__(16) u16 tb[64 * 68];
  const int col = threadIdx.x & 63;
  const int rowo = threadIdx.x >> 6;
#pragma unroll 1
  for (int t2 = 0; t2 < 2; t2++) {
    const int tile = bid * 2 + t2;
    const int z = tile >> 8, t = tile & 255;
    const float* W = (z == 0) ? w0 : (z == 1) ? w1 : (z == 2) ? w2 : w3;
    u16* O = out + z * 1048576;
    const int n0 = (t & 15) * 64, k0 = (t >> 4) * 64;
#pragma unroll
    for (int r = 0; r < 16; r++) {
      int kl = r * 4 + rowo;
      tb[col * 68 + kl] = f2bf(W[(k0 + kl) * 1024 + n0 + col]);
    }
    __syncthreads();
#pragma unroll
    for (int r = 0; r < 16; r++) {
      int nl = r * 4 + rowo;
      O[(n0 + nl) * 1024 + k0 + col] = tb[nl * 68 + col];
    }
    __syncthreads();
  }
}

// -------- QKV GEMM: 128x128 tiles, register-prefetch double-buffered staging --------
// XCD-aware decode: xcd = id%8 owns 8 m-panels x 12 (n,z)-panels
__global__ __launch_bounds__(256, 3) void gemm128(const u16* __restrict__ A,
                                                  const u16* __restrict__ BtBase,
                                                  u16* __restrict__ outp) {
  __shared__ __align__(16) u16 smem[18432];   // sA(8192)+sB(8192) u16; epilogue retile 128x144
  u16* sA = smem;
  u16* sB = smem + 8192;
  const int tid = threadIdx.x, lane = tid & 63, wave = tid >> 6;
  const int l15 = lane & 15, quad = lane >> 4;
  const int wm = (wave >> 1) * 64, wn = (wave & 1) * 64;

  const int id = blockIdx.x + blockIdx.y * 24;
  const int xcd = id & 7, jj = id >> 3;
  const int nz = (jj % 12) + (xcd & 1) * 12;
  const int ymb = (jj / 12) + (xcd >> 1) * 8;
  const int n = nz / 3, z = nz % 3;
  const int m0 = ymb * 128, n0 = n * 128;
  const u16* Ab = A + m0 * 1024;
  const u16* Bb = BtBase + z * 1048576 + n0 * 1024;

  // per-thread staging coords (row, swizzled 16B chunk) for 4 rounds
  int srow[4], soff[4], sdst[4];
#pragma unroll
  for (int r = 0; r < 4; r++) {
    int cc = r * 256 + wave * 64 + lane;
    srow[r] = cc >> 3;
    soff[r] = srow[r] * 1024 + ((cc & 7) ^ (srow[r] & 7)) * 8;
    sdst[r] = cc * 8;
  }

  f32x4 acc[4][4];
  const f32x4 vz = {0.f, 0.f, 0.f, 0.f};
#pragma unroll
  for (int i = 0; i < 4; i++)
#pragma unroll
    for (int j = 0; j < 4; j++) acc[i][j] = vz;

  const int sx = l15 & 7;

  // prologue: stage tile 0 through regs
  uint4 pa[4], pb[4];
#pragma unroll
  for (int r = 0; r < 4; r++) {
    pa[r] = *(const uint4*)(Ab + soff[r]);
    pb[r] = *(const uint4*)(Bb + soff[r]);
  }
#pragma unroll
  for (int r = 0; r < 4; r++) {
    *(uint4*)(sA + sdst[r]) = pa[r];
    *(uint4*)(sB + sdst[r]) = pb[r];
  }

#pragma unroll 1
  for (int kt = 0; kt < 16; kt++) {
    __syncthreads();   // staged tile kt visible
    if (kt < 15) {
      const int ka = (kt + 1) * 64;
#pragma unroll
      for (int r = 0; r < 4; r++) {
        pa[r] = *(const uint4*)(Ab + ka + soff[r]);
        pb[r] = *(const uint4*)(Bb + ka + soff[r]);
      }
    }
#pragma unroll
    for (int kk = 0; kk < 2; kk++) {
      bf16x8 af[4], bg[4];
      int g8 = kk * 4 + quad;
#pragma unroll
      for (int mt = 0; mt < 4; mt++)
        af[mt] = *(const bf16x8*)(sA + (wm + mt * 16 + l15) * 64 + (g8 ^ sx) * 8);
#pragma unroll
      for (int nt = 0; nt < 4; nt++)
        bg[nt] = *(const bf16x8*)(sB + (wn + nt * 16 + l15) * 64 + (g8 ^ sx) * 8);
#pragma unroll
      for (int mt = 0; mt < 4; mt++)
#pragma unroll
        for (int nt = 0; nt < 4; nt++)
          acc[mt][nt] = MFMA16(af[mt], bg[nt], acc[mt][nt]);
    }
    __syncthreads();   // all reads of tile kt done
    if (kt < 15) {
#pragma unroll
      for (int r = 0; r < 4; r++) {
        *(uint4*)(sA + sdst[r]) = pa[r];
        *(uint4*)(sB + sdst[r]) = pb[r];
      }
    }
  }

  if (z == 2) {
    // transpose in LDS (col-major stride 136) then 16B coalesced stores to Vt[b,h,dk,s]
    u16* O = outp + z * 4194304;
#pragma unroll
    for (int mt = 0; mt < 4; mt++)
#pragma unroll
      for (int nt = 0; nt < 4; nt++) {
        int col = wn + nt * 16 + l15;
        int rowb = wm + mt * 16 + quad * 4;
        uint2 p;
        p.x = (u32)f2bf(acc[mt][nt][0]) | ((u32)f2bf(acc[mt][nt][1]) << 16);
        p.y = (u32)f2bf(acc[mt][nt][2]) | ((u32)f2bf(acc[mt][nt][3]) << 16);
        *(uint2*)(smem + col * 136 + rowb) = p;
      }
    __syncthreads();
    const int b = m0 >> 10, sbase = m0 & 1023;
#pragma unroll
    for (int p = 0; p < 8; p++) {
      int g = p * 256 + tid;
      int col = g >> 4, chunk = g & 15;
      uint4 v = *(const uint4*)(smem + col * 136 + chunk * 8);
      int nn = n0 + col, hh = nn >> 6, dk = nn & 63;
      *(uint4*)(O + ((b * 16 + hh) * 64 + dk) * 1024 + sbase + chunk * 8) = v;
    }
  } else {
    // retile [m][n] in LDS (stride 144) then 16B stores
    u16* O = outp + z * 4194304;
    const float scl = (z == 0) ? LOG2E : 1.0f;   // pre-scale Q for exp2-softmax
#pragma unroll
    for (int mt = 0; mt < 4; mt++)
#pragma unroll
      for (int nt = 0; nt < 4; nt++) {
        int rowb = wm + mt * 16 + quad * 4;
        int colb = wn + nt * 16 + l15;
#pragma unroll
        for (int reg = 0; reg < 4; reg++)
          smem[(rowb + reg) * 144 + colb] = f2bf(acc[mt][nt][reg] * scl);
      }
    __syncthreads();
    const int b = m0 >> 10, sbase = m0 & 1023;
#pragma unroll
    for (int p = 0; p < 8; p++) {
      int g = p * 256 + tid;
      int ml = g >> 4, c = g & 15;
      uint4 v = *(const uint4*)(smem + ml * 144 + c * 8);
      int nn = n0 + c * 8, hh = nn >> 6, dk = nn & 63;
      *(uint4*)(O + (b * 16 + hh) * 65536 + (sbase + ml) * 64 + dk) = v;
    }
  }
}

// ---------------- flash attention: block = (b,h) x 128 q-rows; wave = 32q x 64keys ----------------
__global__ __launch_bounds__(256) void attn(const u16* __restrict__ Q, const u16* __restrict__ K,
                                            const u16* __restrict__ V, const float* __restrict__ emb,
                                            u16* __restrict__ ctx) {
  __shared__ __align__(16) u16 sK[64 * 64];
  __shared__ __align__(16) u16 sV[64 * 64];     // V^T tile [d][s_local]
  __shared__ __align__(16) u16 sP[128 * 72];    // P [qrow][key], stride 72
  __shared__ __align__(16) float4 bt4[1156];    // replicated bias*log2e
  const int tid = threadIdx.x, lane = tid & 63, wave = tid >> 6;
  const int l15 = lane & 15, quad = lane >> 4;
  const int bh = blockIdx.x, qt = blockIdx.y;
  const int h = bh & 15, b = bh >> 4;
  const u16* Qp = Q + bh * 65536 + qt * 8192;
  const u16* Kp = K + bh * 65536;
  const u16* Vp = V + bh * 65536;
  const int sx = l15 & 7;

  bf16x8 aq[2][2];
#pragma unroll
  for (int u = 0; u < 2; u++)
#pragma unroll
    for (int kk = 0; kk < 2; kk++)
      aq[u][kk] = *(const bf16x8*)(Qp + (wave * 32 + u * 16 + l15) * 64 + kk * 32 + quad * 8);

  for (int i = tid; i < 1156; i += 256) {
    int rp0 = i - 127 - qt * 128;
    float4 v;
    v.x = emb[t5_bucket(rp0)     * 16 + h] * LOG2E;
    v.y = emb[t5_bucket(rp0 + 1) * 16 + h] * LOG2E;
    v.z = emb[t5_bucket(rp0 + 2) * 16 + h] * LOG2E;
    v.w = emb[t5_bucket(rp0 + 3) * 16 + h] * LOG2E;
    bt4[i] = v;
  }
  const float bias_pos = emb[31 * 16 + h] * LOG2E;  // rp >= 91
  const float bias_neg = emb[15 * 16 + h] * LOG2E;  // rp <= -91

  float2 ls2[2] = {{0.f, 0.f}, {0.f, 0.f}};
  f32x4 oc[2][4];
  const f32x4 vzero = {0.f, 0.f, 0.f, 0.f};
#pragma unroll
  for (int u = 0; u < 2; u++)
#pragma unroll
    for (int nt = 0; nt < 4; nt++) oc[u][nt] = vzero;

  __syncthreads();   // bt4 ready

#pragma unroll 1
  for (int j = 0; j < 16; j++) {
    const u16* Kj = Kp + j * 4096;
#pragma unroll
    for (int r = 0; r < 2; r++) {
      int cb = r * 256 + wave * 64;
      int cc = cb + lane;
      int row = cc >> 3, c8 = (cc & 7) ^ (row & 7);
      gld16(sK + cb * 8, Kj + row * 64 + c8 * 8);
      gld16(sV + cb * 8, Vp + row * 1024 + j * 64 + c8 * 8);
    }
    __syncthreads();

    // S^T = K.Q^T + bias  (lane: key = mt*16+quad*4+reg, qrow = u*16+l15)
    f32x4 sc[4][2];
    const int rp_min = j * 64 - qt * 128 - 127;
    const int rp_max = j * 64 + 63 - qt * 128;
    if (rp_min >= 91) {
#pragma unroll
      for (int mt = 0; mt < 4; mt++)
#pragma unroll
        for (int u = 0; u < 2; u++) { sc[mt][u][0] = bias_pos; sc[mt][u][1] = bias_pos; sc[mt][u][2] = bias_pos; sc[mt][u][3] = bias_pos; }
    } else if (rp_max <= -91) {
#pragma unroll
      for (int mt = 0; mt < 4; mt++)
#pragma unroll
        for (int u = 0; u < 2; u++) { sc[mt][u][0] = bias_neg; sc[mt][u][1] = bias_neg; sc[mt][u][2] = bias_neg; sc[mt][u][3] = bias_neg; }
    } else {
#pragma unroll
      for (int mt = 0; mt < 4; mt++)
#pragma unroll
        for (int u = 0; u < 2; u++) {
          int idx = j * 64 + mt * 16 + quad * 4 - wave * 32 - u * 16 - l15 + 127;
          float4 bv4 = bt4[idx];
          sc[mt][u][0] = bv4.x; sc[mt][u][1] = bv4.y; sc[mt][u][2] = bv4.z; sc[mt][u][3] = bv4.w;
        }
    }
#pragma unroll
    for (int kk = 0; kk < 2; kk++) {
      bf16x8 ak[4];
      int g8 = kk * 4 + quad;
#pragma unroll
      for (int mt = 0; mt < 4; mt++)
        ak[mt] = *(const bf16x8*)(sK + (mt * 16 + l15) * 64 + (g8 ^ sx) * 8);
#pragma unroll
      for (int mt = 0; mt < 4; mt++)
#pragma unroll
        for (int u = 0; u < 2; u++)
          sc[mt][u] = MFMA16(ak[mt], aq[u][kk], sc[mt][u]);
    }

    // softmax: truncate-to-bf16 P; lsum accumulated from truncated values
#pragma unroll
    for (int u = 0; u < 2; u++) {
      const int prow = wave * 32 + u * 16 + l15;
#pragma unroll
      for (int mt = 0; mt < 4; mt++) {
        u32 b0 = __float_as_uint(__builtin_amdgcn_exp2f(sc[mt][u][0]));
        u32 b1 = __float_as_uint(__builtin_amdgcn_exp2f(sc[mt][u][1]));
        u32 b2 = __float_as_uint(__builtin_amdgcn_exp2f(sc[mt][u][2]));
        u32 b3 = __float_as_uint(__builtin_amdgcn_exp2f(sc[mt][u][3]));
        u32 t0 = b0 & 0xFFFF0000u, t1 = b1 & 0xFFFF0000u;
        u32 t2 = b2 & 0xFFFF0000u, t3 = b3 & 0xFFFF0000u;
        ls2[u].x += __uint_as_float(t0) + __uint_as_float(t2);
        ls2[u].y += __uint_as_float(t1) + __uint_as_float(t3);
        uint2 pk;
        pk.x = (t0 >> 16) | t1;
        pk.y = (t2 >> 16) | t3;
        *(uint2*)(sP + prow * 72 + mt * 16 + quad * 4) = pk;
      }
    }
    asm volatile("s_waitcnt lgkmcnt(0)" ::: "memory");   // wave-private P write->read

    // O += P.V
#pragma unroll
    for (int kk = 0; kk < 2; kk++) {
      bf16x8 ap[2];
      int g8 = kk * 4 + quad;
#pragma unroll
      for (int u = 0; u < 2; u++)
        ap[u] = *(const bf16x8*)(sP + (wave * 32 + u * 16 + l15) * 72 + kk * 32 + quad * 8);
#pragma unroll
      for (int nt = 0; nt < 4; nt++) {
        bf16x8 bv = *(const bf16x8*)(sV + (nt * 16 + l15) * 64 + (g8 ^ sx) * 8);
#pragma unroll
        for (int u = 0; u < 2; u++)
          oc[u][nt] = MFMA16(ap[u], bv, oc[u][nt]);
      }
    }
    __syncthreads();
  }

  float lsum[2];
#pragma unroll
  for (int u = 0; u < 2; u++) {
    lsum[u] = ls2[u].x + ls2[u].y;
    lsum[u] += __shfl_xor(lsum[u], 16, 64);
    lsum[u] += __shfl_xor(lsum[u], 32, 64);
  }
  float linv[2][4];
#pragma unroll
  for (int u = 0; u < 2; u++)
#pragma unroll
    for (int reg = 0; reg < 4; reg++)
      linv[u][reg] = __builtin_amdgcn_rcpf(__shfl(lsum[u], quad * 4 + reg, 64));

  u16* cb2 = ctx + b * 1048576 + (qt * 128 + wave * 32) * 1024 + h * 64;
#pragma unroll
  for (int u = 0; u < 2; u++)
#pragma unroll
    for (int nt = 0; nt < 4; nt++)
#pragma unroll
      for (int reg = 0; reg < 4; reg++)
        cb2[(u * 16 + quad * 4 + reg) * 1024 + nt * 16 + l15] = f2bf(oc[u][nt][reg] * linv[u][reg]);
}

// -------- out-proj GEMM: 128x128 tiles, reg-prefetch double-buffer, fp32 out --------
__global__ __launch_bounds__(256, 2) void gemm_o(const u16* __restrict__ A,
                                                 const u16* __restrict__ Bt,
                                                 float* __restrict__ O) {
  __shared__ __align__(16) u16 sA[128 * 64];
  __shared__ __align__(16) u16 sB[128 * 64];
  const int tid = threadIdx.x, lane = tid & 63, wave = tid >> 6;
  const int l15 = lane & 15, quad = lane >> 4;
  const int wm = (wave >> 1) * 64, wn = (wave & 1) * 64;
  const int m0 = blockIdx.x * 128, n0 = blockIdx.y * 128;   // id%8 = m%8 -> XCD: A 1MB + B 2MB in L2
  const u16* Ab = A + m0 * 1024;
  const u16* Bb = Bt + n0 * 1024;

  int srow[4], soff[4], sdst[4];
#pragma unroll
  for (int r = 0; r < 4; r++) {
    int cc = r * 256 + wave * 64 + lane;
    srow[r] = cc >> 3;
    soff[r] = srow[r] * 1024 + ((cc & 7) ^ (srow[r] & 7)) * 8;
    sdst[r] = cc * 8;
  }

  f32x4 acc[4][4];
  const f32x4 vz = {0.f, 0.f, 0.f, 0.f};
#pragma unroll
  for (int i = 0; i < 4; i++)
#pragma unroll
    for (int j = 0; j < 4; j++) acc[i][j] = vz;

  const int sx = l15 & 7;

  uint4 pa[4], pb[4];
#pragma unroll
  for (int r = 0; r < 4; r++) {
    pa[r] = *(const uint4*)(Ab + soff[r]);
    pb[r] = *(const uint4*)(Bb + soff[r]);
  }
#pragma unroll
  for (int r = 0; r < 4; r++) {
    *(uint4*)(sA + sdst[r]) = pa[r];
    *(uint4*)(sB + sdst[r]) = pb[r];
  }

#pragma unroll 1
  for (int kt = 0; kt < 16; kt++) {
    __syncthreads();
    if (kt < 15) {
      const int ka = (kt + 1) * 64;
#pragma unroll
      for (int r = 0; r < 4; r++) {
        pa[r] = *(const uint4*)(Ab + ka + soff[r]);
        pb[r] = *(const uint4*)(Bb + ka + soff[r]);
      }
    }
#pragma unroll
    for (int kk = 0; kk < 2; kk++) {
      bf16x8 af[4], bg[4];
      int g8 = kk * 4 + quad;
#pragma unroll
      for (int mt = 0; mt < 4; mt++)
        af[mt] = *(const bf16x8*)(sA + (wm + mt * 16 + l15) * 64 + (g8 ^ sx) * 8);
#pragma unroll
      for (int nt = 0; nt < 4; nt++)
        bg[nt] = *(const bf16x8*)(sB + (wn + nt * 16 + l15) * 64 + (g8 ^ sx) * 8);
#pragma unroll
      for (int mt = 0; mt < 4; mt++)
#pragma unroll
        for (int nt = 0; nt < 4; nt++)
          acc[mt][nt] = MFMA16(af[mt], bg[nt], acc[mt][nt]);
    }
    __syncthreads();
    if (kt < 15) {
#pragma unroll
      for (int r = 0; r < 4; r++) {
        *(uint4*)(sA + sdst[r]) = pa[r];
        *(uint4*)(sB + sdst[r]) = pb[r];
      }
    }
  }

#pragma unroll
  for (int mt = 0; mt < 4; mt++)
#pragma unroll
    for (int nt = 0; nt < 4; nt++)
#pragma unroll
      for (int reg = 0; reg < 4; reg++) {
        int row = m0 + wm + mt * 16 + quad * 4 + reg;
        int col = n0 + wn + nt * 16 + l15;
        O[row * 1024 + col] = acc[mt][nt][reg];
      }
}

extern "C" void kernel_launch(void* const* d_in, const int* in_sizes, int n_in,
                              void* d_out, int out_size, void* d_ws, size_t ws_size,
                              hipStream_t stream) {
  (void)in_sizes; (void)n_in; (void)out_size; (void)ws_size;
  const float* X   = (const float*)d_in[0];
  const float* Wq  = (const float*)d_in[1];
  const float* Wk  = (const float*)d_in[2];
  const float* Wv  = (const float*)d_in[3];
  const float* Wo  = (const float*)d_in[4];
  const float* emb = (const float*)d_in[5];

  char* ws = (char*)d_ws;
  u16* Xb  = (u16*)(ws);                              // 8 MB: X bf16 [4096][1024]
  u16* Wt  = (u16*)(ws + (8u  << 20));                // 8 MB: Wq^T,Wk^T,Wv^T,Wo^T bf16
  u16* Qb  = (u16*)(ws + (16u << 20));                // 8+8+8 MB: Q(log2e-scaled), K, Vt
  u16* Ctx = (u16*)(ws + (40u << 20));                // 8 MB: attention output bf16

  prep<<<1024, 256, 0, stream>>>((const float4*)X, (ushort4*)Xb, Wq, Wk, Wv, Wo, Wt);
  gemm128<<<dim3(24, 32), 256, 0, stream>>>(Xb, Wt, Qb);
  attn<<<dim3(64, 8), 256, 0, stream>>>(Qb, Qb + 4194304, Qb + 2 * 4194304, emb, Ctx);
  gemm_o<<<dim3(32, 8), 256, 0, stream>>>(Ctx, Wt + 3 * 1048576, (float*)d_out);
}

// Round 6
// 269.543 us; speedup vs baseline: 1.0887x; 1.0887x over previous
//
#include <hip/hip_runtime.h>

typedef unsigned short u16;
typedef unsigned int u32;
typedef __bf16 bf16x8 __attribute__((ext_vector_type(8)));
typedef float f32x4 __attribute__((ext_vector_type(4)));

#define MFMA16(a, b, c) __builtin_amdgcn_mfma_f32_16x16x32_bf16(a, b, c, 0, 0, 0)
#define LOG2E 1.4426950408889634f

__device__ __forceinline__ u16 f2bf(float f) {
  u32 u = __float_as_uint(f);
  u += 0x7FFFu + ((u >> 16) & 1u);   // RNE to bf16
  return (u16)(u >> 16);
}

__device__ __forceinline__ void gld16(u16* lds, const u16* g) {
  __builtin_amdgcn_global_load_lds((const __attribute__((address_space(1))) void*)g,
                                   (__attribute__((address_space(3))) void*)lds,
                                   16, 0, 0);
}

// Exact integer replication of T5 bucketing (bidirectional, 32 buckets, max_dist 128).
__device__ __forceinline__ int t5_bucket(int rp) {
  int ret = rp > 0 ? 16 : 0;
  int a = rp < 0 ? -rp : rp;
  int b;
  if      (a <  8) b = a;
  else if (a < 12) b = 8;
  else if (a < 16) b = 9;
  else if (a < 23) b = 10;
  else if (a < 32) b = 11;
  else if (a < 46) b = 12;
  else if (a < 64) b = 13;
  else if (a < 91) b = 14;
  else             b = 15;
  return ret + b;
}

// ---------------- fused prep, grid 1024: blocks 0..511 X cvt, 512..1023 W cvt ----
__global__ __launch_bounds__(256) void prep(const float4* __restrict__ X, ushort4* __restrict__ Xb,
                                            const float* __restrict__ w0, const float* __restrict__ w1,
                                            const float* __restrict__ w2, const float* __restrict__ w3,
                                            u16* __restrict__ out) {
  int bid = blockIdx.x;
  if (bid < 512) {
#pragma unroll
    for (int i = 0; i < 8; i++) {
      int g = bid * 2048 + i * 256 + threadIdx.x;
      float4 v = X[g];
      ushort4 o;
      o.x = f2bf(v.x); o.y = f2bf(v.y); o.z = f2bf(v.z); o.w = f2bf(v.w);
      Xb[g] = o;
    }
    return;
  }
  bid -= 512;
  __shared__ __align__(16) u16 tb[64 * 68];
  const int col = threadIdx.x & 63;
  const int rowo = threadIdx.x >> 6;
#pragma unroll 1
  for (int t2 = 0; t2 < 2; t2++) {
    const int tile = bid * 2 + t2;
    const int z = tile >> 8, t = tile & 255;
    const float* W = (z == 0) ? w0 : (z == 1) ? w1 : (z == 2) ? w2 : w3;
    u16* O = out + z * 1048576;
    const int n0 = (t & 15) * 64, k0 = (t >> 4) * 64;
#pragma unroll
    for (int r = 0; r < 16; r++) {
      int kl = r * 4 + rowo;
      tb[col * 68 + kl] = f2bf(W[(k0 + kl) * 1024 + n0 + col]);
    }
    __syncthreads();
#pragma unroll
    for (int r = 0; r < 16; r++) {
      int nl = r * 4 + rowo;
      O[(n0 + nl) * 1024 + k0 + col] = tb[nl * 68 + col];
    }
    __syncthreads();
  }
}

// -------- QKV GEMM: 128x128 tiles, register-prefetch double-buffered staging --------
// XCD-aware decode: xcd = id%8 owns 8 m-panels x 12 (n,z)-panels
// NOTE: no launch_bounds min-waves arg — on gfx950 it caps the UNIFIED VGPR+AGPR
// file and spilled acc+prefetch to scratch (R5: 400MB WRITE_SIZE, 2.8x regression).
__global__ __launch_bounds__(256) void gemm128(const u16* __restrict__ A,
                                               const u16* __restrict__ BtBase,
                                               u16* __restrict__ outp) {
  __shared__ __align__(16) u16 smem[18432];   // sA(8192)+sB(8192) u16; epilogue retile 128x144
  u16* sA = smem;
  u16* sB = smem + 8192;
  const int tid = threadIdx.x, lane = tid & 63, wave = tid >> 6;
  const int l15 = lane & 15, quad = lane >> 4;
  const int wm = (wave >> 1) * 64, wn = (wave & 1) * 64;

  const int id = blockIdx.x + blockIdx.y * 24;
  const int xcd = id & 7, jj = id >> 3;
  const int nz = (jj % 12) + (xcd & 1) * 12;
  const int ymb = (jj / 12) + (xcd >> 1) * 8;
  const int n = nz / 3, z = nz % 3;
  const int m0 = ymb * 128, n0 = n * 128;
  const u16* Ab = A + m0 * 1024;
  const u16* Bb = BtBase + z * 1048576 + n0 * 1024;

  // per-thread staging coords (row, swizzled 16B chunk) for 4 rounds
  int soff[4], sdst[4];
#pragma unroll
  for (int r = 0; r < 4; r++) {
    int cc = r * 256 + wave * 64 + lane;
    int row = cc >> 3;
    soff[r] = row * 1024 + ((cc & 7) ^ (row & 7)) * 8;
    sdst[r] = cc * 8;
  }

  f32x4 acc[4][4];
  const f32x4 vz = {0.f, 0.f, 0.f, 0.f};
#pragma unroll
  for (int i = 0; i < 4; i++)
#pragma unroll
    for (int j = 0; j < 4; j++) acc[i][j] = vz;

  const int sx = l15 & 7;

  // prologue: stage tile 0 through regs
  uint4 pa[4], pb[4];
#pragma unroll
  for (int r = 0; r < 4; r++) {
    pa[r] = *(const uint4*)(Ab + soff[r]);
    pb[r] = *(const uint4*)(Bb + soff[r]);
  }
#pragma unroll
  for (int r = 0; r < 4; r++) {
    *(uint4*)(sA + sdst[r]) = pa[r];
    *(uint4*)(sB + sdst[r]) = pb[r];
  }

#pragma unroll 1
  for (int kt = 0; kt < 16; kt++) {
    __syncthreads();   // staged tile kt visible
    if (kt < 15) {
      const int ka = (kt + 1) * 64;
#pragma unroll
      for (int r = 0; r < 4; r++) {
        pa[r] = *(const uint4*)(Ab + ka + soff[r]);
        pb[r] = *(const uint4*)(Bb + ka + soff[r]);
      }
    }
#pragma unroll
    for (int kk = 0; kk < 2; kk++) {
      bf16x8 af[4], bg[4];
      int g8 = kk * 4 + quad;
#pragma unroll
      for (int mt = 0; mt < 4; mt++)
        af[mt] = *(const bf16x8*)(sA + (wm + mt * 16 + l15) * 64 + (g8 ^ sx) * 8);
#pragma unroll
      for (int nt = 0; nt < 4; nt++)
        bg[nt] = *(const bf16x8*)(sB + (wn + nt * 16 + l15) * 64 + (g8 ^ sx) * 8);
#pragma unroll
      for (int mt = 0; mt < 4; mt++)
#pragma unroll
        for (int nt = 0; nt < 4; nt++)
          acc[mt][nt] = MFMA16(af[mt], bg[nt], acc[mt][nt]);
    }
    __syncthreads();   // all reads of tile kt done
    if (kt < 15) {
#pragma unroll
      for (int r = 0; r < 4; r++) {
        *(uint4*)(sA + sdst[r]) = pa[r];
        *(uint4*)(sB + sdst[r]) = pb[r];
      }
    }
  }

  if (z == 2) {
    // transpose in LDS (col-major stride 136) then 16B coalesced stores to Vt[b,h,dk,s]
    u16* O = outp + z * 4194304;
#pragma unroll
    for (int mt = 0; mt < 4; mt++)
#pragma unroll
      for (int nt = 0; nt < 4; nt++) {
        int col = wn + nt * 16 + l15;
        int rowb = wm + mt * 16 + quad * 4;
        uint2 p;
        p.x = (u32)f2bf(acc[mt][nt][0]) | ((u32)f2bf(acc[mt][nt][1]) << 16);
        p.y = (u32)f2bf(acc[mt][nt][2]) | ((u32)f2bf(acc[mt][nt][3]) << 16);
        *(uint2*)(smem + col * 136 + rowb) = p;
      }
    __syncthreads();
    const int b = m0 >> 10, sbase = m0 & 1023;
#pragma unroll
    for (int p = 0; p < 8; p++) {
      int g = p * 256 + tid;
      int col = g >> 4, chunk = g & 15;
      uint4 v = *(const uint4*)(smem + col * 136 + chunk * 8);
      int nn = n0 + col, hh = nn >> 6, dk = nn & 63;
      *(uint4*)(O + ((b * 16 + hh) * 64 + dk) * 1024 + sbase + chunk * 8) = v;
    }
  } else {
    // retile [m][n] in LDS (stride 144) then 16B stores
    u16* O = outp + z * 4194304;
    const float scl = (z == 0) ? LOG2E : 1.0f;   // pre-scale Q for exp2-softmax
#pragma unroll
    for (int mt = 0; mt < 4; mt++)
#pragma unroll
      for (int nt = 0; nt < 4; nt++) {
        int rowb = wm + mt * 16 + quad * 4;
        int colb = wn + nt * 16 + l15;
#pragma unroll
        for (int reg = 0; reg < 4; reg++)
          smem[(rowb + reg) * 144 + colb] = f2bf(acc[mt][nt][reg] * scl);
      }
    __syncthreads();
    const int b = m0 >> 10, sbase = m0 & 1023;
#pragma unroll
    for (int p = 0; p < 8; p++) {
      int g = p * 256 + tid;
      int ml = g >> 4, c = g & 15;
      uint4 v = *(const uint4*)(smem + ml * 144 + c * 8);
      int nn = n0 + c * 8, hh = nn >> 6, dk = nn & 63;
      *(uint4*)(O + (b * 16 + hh) * 65536 + (sbase + ml) * 64 + dk) = v;
    }
  }
}

// ---------------- flash attention: block = (b,h) x 128 q-rows; wave = 32q x 64keys ----------------
__global__ __launch_bounds__(256) void attn(const u16* __restrict__ Q, const u16* __restrict__ K,
                                            const u16* __restrict__ V, const float* __restrict__ emb,
                                            u16* __restrict__ ctx) {
  __shared__ __align__(16) u16 sK[64 * 64];
  __shared__ __align__(16) u16 sV[64 * 64];     // V^T tile [d][s_local]
  __shared__ __align__(16) u16 sP[128 * 72];    // P [qrow][key], stride 72
  __shared__ __align__(16) float4 bt4[1156];    // replicated bias*log2e
  const int tid = threadIdx.x, lane = tid & 63, wave = tid >> 6;
  const int l15 = lane & 15, quad = lane >> 4;
  const int bh = blockIdx.x, qt = blockIdx.y;
  const int h = bh & 15, b = bh >> 4;
  const u16* Qp = Q + bh * 65536 + qt * 8192;
  const u16* Kp = K + bh * 65536;
  const u16* Vp = V + bh * 65536;
  const int sx = l15 & 7;

  bf16x8 aq[2][2];
#pragma unroll
  for (int u = 0; u < 2; u++)
#pragma unroll
    for (int kk = 0; kk < 2; kk++)
      aq[u][kk] = *(const bf16x8*)(Qp + (wave * 32 + u * 16 + l15) * 64 + kk * 32 + quad * 8);

  for (int i = tid; i < 1156; i += 256) {
    int rp0 = i - 127 - qt * 128;
    float4 v;
    v.x = emb[t5_bucket(rp0)     * 16 + h] * LOG2E;
    v.y = emb[t5_bucket(rp0 + 1) * 16 + h] * LOG2E;
    v.z = emb[t5_bucket(rp0 + 2) * 16 + h] * LOG2E;
    v.w = emb[t5_bucket(rp0 + 3) * 16 + h] * LOG2E;
    bt4[i] = v;
  }
  const float bias_pos = emb[31 * 16 + h] * LOG2E;  // rp >= 91
  const float bias_neg = emb[15 * 16 + h] * LOG2E;  // rp <= -91

  float2 ls2[2] = {{0.f, 0.f}, {0.f, 0.f}};
  f32x4 oc[2][4];
  const f32x4 vzero = {0.f, 0.f, 0.f, 0.f};
#pragma unroll
  for (int u = 0; u < 2; u++)
#pragma unroll
    for (int nt = 0; nt < 4; nt++) oc[u][nt] = vzero;

  __syncthreads();   // bt4 ready

#pragma unroll 1
  for (int j = 0; j < 16; j++) {
    const u16* Kj = Kp + j * 4096;
#pragma unroll
    for (int r = 0; r < 2; r++) {
      int cb = r * 256 + wave * 64;
      int cc = cb + lane;
      int row = cc >> 3, c8 = (cc & 7) ^ (row & 7);
      gld16(sK + cb * 8, Kj + row * 64 + c8 * 8);
      gld16(sV + cb * 8, Vp + row * 1024 + j * 64 + c8 * 8);
    }
    __syncthreads();

    // S^T = K.Q^T + bias  (lane: key = mt*16+quad*4+reg, qrow = u*16+l15)
    f32x4 sc[4][2];
    const int rp_min = j * 64 - qt * 128 - 127;
    const int rp_max = j * 64 + 63 - qt * 128;
    if (rp_min >= 91) {
#pragma unroll
      for (int mt = 0; mt < 4; mt++)
#pragma unroll
        for (int u = 0; u < 2; u++) { sc[mt][u][0] = bias_pos; sc[mt][u][1] = bias_pos; sc[mt][u][2] = bias_pos; sc[mt][u][3] = bias_pos; }
    } else if (rp_max <= -91) {
#pragma unroll
      for (int mt = 0; mt < 4; mt++)
#pragma unroll
        for (int u = 0; u < 2; u++) { sc[mt][u][0] = bias_neg; sc[mt][u][1] = bias_neg; sc[mt][u][2] = bias_neg; sc[mt][u][3] = bias_neg; }
    } else {
#pragma unroll
      for (int mt = 0; mt < 4; mt++)
#pragma unroll
        for (int u = 0; u < 2; u++) {
          int idx = j * 64 + mt * 16 + quad * 4 - wave * 32 - u * 16 - l15 + 127;
          float4 bv4 = bt4[idx];
          sc[mt][u][0] = bv4.x; sc[mt][u][1] = bv4.y; sc[mt][u][2] = bv4.z; sc[mt][u][3] = bv4.w;
        }
    }
#pragma unroll
    for (int kk = 0; kk < 2; kk++) {
      bf16x8 ak[4];
      int g8 = kk * 4 + quad;
#pragma unroll
      for (int mt = 0; mt < 4; mt++)
        ak[mt] = *(const bf16x8*)(sK + (mt * 16 + l15) * 64 + (g8 ^ sx) * 8);
#pragma unroll
      for (int mt = 0; mt < 4; mt++)
#pragma unroll
        for (int u = 0; u < 2; u++)
          sc[mt][u] = MFMA16(ak[mt], aq[u][kk], sc[mt][u]);
    }

    // softmax: truncate-to-bf16 P; lsum accumulated from truncated values
#pragma unroll
    for (int u = 0; u < 2; u++) {
      const int prow = wave * 32 + u * 16 + l15;
#pragma unroll
      for (int mt = 0; mt < 4; mt++) {
        u32 b0 = __float_as_uint(__builtin_amdgcn_exp2f(sc[mt][u][0]));
        u32 b1 = __float_as_uint(__builtin_amdgcn_exp2f(sc[mt][u][1]));
        u32 b2 = __float_as_uint(__builtin_amdgcn_exp2f(sc[mt][u][2]));
        u32 b3 = __float_as_uint(__builtin_amdgcn_exp2f(sc[mt][u][3]));
        u32 t0 = b0 & 0xFFFF0000u, t1 = b1 & 0xFFFF0000u;
        u32 t2 = b2 & 0xFFFF0000u, t3 = b3 & 0xFFFF0000u;
        ls2[u].x += __uint_as_float(t0) + __uint_as_float(t2);
        ls2[u].y += __uint_as_float(t1) + __uint_as_float(t3);
        uint2 pk;
        pk.x = (t0 >> 16) | t1;
        pk.y = (t2 >> 16) | t3;
        *(uint2*)(sP + prow * 72 + mt * 16 + quad * 4) = pk;
      }
    }
    asm volatile("s_waitcnt lgkmcnt(0)" ::: "memory");   // wave-private P write->read

    // O += P.V
#pragma unroll
    for (int kk = 0; kk < 2; kk++) {
      bf16x8 ap[2];
      int g8 = kk * 4 + quad;
#pragma unroll
      for (int u = 0; u < 2; u++)
        ap[u] = *(const bf16x8*)(sP + (wave * 32 + u * 16 + l15) * 72 + kk * 32 + quad * 8);
#pragma unroll
      for (int nt = 0; nt < 4; nt++) {
        bf16x8 bv = *(const bf16x8*)(sV + (nt * 16 + l15) * 64 + (g8 ^ sx) * 8);
#pragma unroll
        for (int u = 0; u < 2; u++)
          oc[u][nt] = MFMA16(ap[u], bv, oc[u][nt]);
      }
    }
    __syncthreads();
  }

  float lsum[2];
#pragma unroll
  for (int u = 0; u < 2; u++) {
    lsum[u] = ls2[u].x + ls2[u].y;
    lsum[u] += __shfl_xor(lsum[u], 16, 64);
    lsum[u] += __shfl_xor(lsum[u], 32, 64);
  }
  float linv[2][4];
#pragma unroll
  for (int u = 0; u < 2; u++)
#pragma unroll
    for (int reg = 0; reg < 4; reg++)
      linv[u][reg] = __builtin_amdgcn_rcpf(__shfl(lsum[u], quad * 4 + reg, 64));

  u16* cb2 = ctx + b * 1048576 + (qt * 128 + wave * 32) * 1024 + h * 64;
#pragma unroll
  for (int u = 0; u < 2; u++)
#pragma unroll
    for (int nt = 0; nt < 4; nt++)
#pragma unroll
      for (int reg = 0; reg < 4; reg++)
        cb2[(u * 16 + quad * 4 + reg) * 1024 + nt * 16 + l15] = f2bf(oc[u][nt][reg] * linv[u][reg]);
}

// -------- out-proj GEMM: 128x128 tiles, reg-prefetch double-buffer, fp32 out --------
__global__ __launch_bounds__(256) void gemm_o(const u16* __restrict__ A,
                                              const u16* __restrict__ Bt,
                                              float* __restrict__ O) {
  __shared__ __align__(16) u16 sA[128 * 64];
  __shared__ __align__(16) u16 sB[128 * 64];
  const int tid = threadIdx.x, lane = tid & 63, wave = tid >> 6;
  const int l15 = lane & 15, quad = lane >> 4;
  const int wm = (wave >> 1) * 64, wn = (wave & 1) * 64;
  const int m0 = blockIdx.x * 128, n0 = blockIdx.y * 128;   // id%8 = m%8 -> XCD: A 1MB + B 2MB in L2
  const u16* Ab = A + m0 * 1024;
  const u16* Bb = Bt + n0 * 1024;

  int soff[4], sdst[4];
#pragma unroll
  for (int r = 0; r < 4; r++) {
    int cc = r * 256 + wave * 64 + lane;
    int row = cc >> 3;
    soff[r] = row * 1024 + ((cc & 7) ^ (row & 7)) * 8;
    sdst[r] = cc * 8;
  }

  f32x4 acc[4][4];
  const f32x4 vz = {0.f, 0.f, 0.f, 0.f};
#pragma unroll
  for (int i = 0; i < 4; i++)
#pragma unroll
    for (int j = 0; j < 4; j++) acc[i][j] = vz;

  const int sx = l15 & 7;

  uint4 pa[4], pb[4];
#pragma unroll
  for (int r = 0; r < 4; r++) {
    pa[r] = *(const uint4*)(Ab + soff[r]);
    pb[r] = *(const uint4*)(Bb + soff[r]);
  }
#pragma unroll
  for (int r = 0; r < 4; r++) {
    *(uint4*)(sA + sdst[r]) = pa[r];
    *(uint4*)(sB + sdst[r]) = pb[r];
  }

#pragma unroll 1
  for (int kt = 0; kt < 16; kt++) {
    __syncthreads();
    if (kt < 15) {
      const int ka = (kt + 1) * 64;
#pragma unroll
      for (int r = 0; r < 4; r++) {
        pa[r] = *(const uint4*)(Ab + ka + soff[r]);
        pb[r] = *(const uint4*)(Bb + ka + soff[r]);
      }
    }
#pragma unroll
    for (int kk = 0; kk < 2; kk++) {
      bf16x8 af[4], bg[4];
      int g8 = kk * 4 + quad;
#pragma unroll
      for (int mt = 0; mt < 4; mt++)
        af[mt] = *(const bf16x8*)(sA + (wm + mt * 16 + l15) * 64 + (g8 ^ sx) * 8);
#pragma unroll
      for (int nt = 0; nt < 4; nt++)
        bg[nt] = *(const bf16x8*)(sB + (wn + nt * 16 + l15) * 64 + (g8 ^ sx) * 8);
#pragma unroll
      for (int mt = 0; mt < 4; mt++)
#pragma unroll
        for (int nt = 0; nt < 4; nt++)
          acc[mt][nt] = MFMA16(af[mt], bg[nt], acc[mt][nt]);
    }
    __syncthreads();
    if (kt < 15) {
#pragma unroll
      for (int r = 0; r < 4; r++) {
        *(uint4*)(sA + sdst[r]) = pa[r];
        *(uint4*)(sB + sdst[r]) = pb[r];
      }
    }
  }

#pragma unroll
  for (int mt = 0; mt < 4; mt++)
#pragma unroll
    for (int nt = 0; nt < 4; nt++)
#pragma unroll
      for (int reg = 0; reg < 4; reg++) {
        int row = m0 + wm + mt * 16 + quad * 4 + reg;
        int col = n0 + wn + nt * 16 + l15;
        O[row * 1024 + col] = acc[mt][nt][reg];
      }
}

extern "C" void kernel_launch(void* const* d_in, const int* in_sizes, int n_in,
                              void* d_out, int out_size, void* d_ws, size_t ws_size,
                              hipStream_t stream) {
  (void)in_sizes; (void)n_in; (void)out_size; (void)ws_size;
  const float* X   = (const float*)d_in[0];
  const float* Wq  = (const float*)d_in[1];
  const float* Wk  = (const float*)d_in[2];
  const float* Wv  = (const float*)d_in[3];
  const float* Wo  = (const float*)d_in[4];
  const float* emb = (const float*)d_in[5];

  char* ws = (char*)d_ws;
  u16* Xb  = (u16*)(ws);                              // 8 MB: X bf16 [4096][1024]
  u16* Wt  = (u16*)(ws + (8u  << 20));                // 8 MB: Wq^T,Wk^T,Wv^T,Wo^T bf16
  u16* Qb  = (u16*)(ws + (16u << 20));                // 8+8+8 MB: Q(log2e-scaled), K, Vt
  u16* Ctx = (u16*)(ws + (40u << 20));                // 8 MB: attention output bf16

  prep<<<1024, 256, 0, stream>>>((const float4*)X, (ushort4*)Xb, Wq, Wk, Wv, Wo, Wt);
  gemm128<<<dim3(24, 32), 256, 0, stream>>>(Xb, Wt, Qb);
  attn<<<dim3(64, 8), 256, 0, stream>>>(Qb, Qb + 4194304, Qb + 2 * 4194304, emb, Ctx);
  gemm_o<<<dim3(32, 8), 256, 0, stream>>>(Ctx, Wt + 3 * 1048576, (float*)d_out);
}

// Round 7
// 164.796 us; speedup vs baseline: 1.7807x; 1.6356x over previous
//
#include <hip/hip_runtime.h>

typedef unsigned short u16;
typedef unsigned int u32;
typedef __bf16 bf16x8 __attribute__((ext_vector_type(8)));
typedef float f32x4 __attribute__((ext_vector_type(4)));

#define MFMA16(a, b, c) __builtin_amdgcn_mfma_f32_16x16x32_bf16(a, b, c, 0, 0, 0)
#define LOG2E 1.4426950408889634f

__device__ __forceinline__ u16 f2bf(float f) {
  u32 u = __float_as_uint(f);
  u += 0x7FFFu + ((u >> 16) & 1u);   // RNE to bf16
  return (u16)(u >> 16);
}

__device__ __forceinline__ void gld16(u16* lds, const u16* g) {
  __builtin_amdgcn_global_load_lds((const __attribute__((address_space(1))) void*)g,
                                   (__attribute__((address_space(3))) void*)lds,
                                   16, 0, 0);
}

// Exact integer replication of T5 bucketing (bidirectional, 32 buckets, max_dist 128).
__device__ __forceinline__ int t5_bucket(int rp) {
  int ret = rp > 0 ? 16 : 0;
  int a = rp < 0 ? -rp : rp;
  int b;
  if      (a <  8) b = a;
  else if (a < 12) b = 8;
  else if (a < 16) b = 9;
  else if (a < 23) b = 10;
  else if (a < 32) b = 11;
  else if (a < 46) b = 12;
  else if (a < 64) b = 13;
  else if (a < 91) b = 14;
  else             b = 15;
  return ret + b;
}

// ---------------- fused prep, grid 1024: blocks 0..511 X cvt, 512..1023 W cvt ----
__global__ __launch_bounds__(256) void prep(const float4* __restrict__ X, ushort4* __restrict__ Xb,
                                            const float* __restrict__ w0, const float* __restrict__ w1,
                                            const float* __restrict__ w2, const float* __restrict__ w3,
                                            u16* __restrict__ out) {
  int bid = blockIdx.x;
  if (bid < 512) {
#pragma unroll
    for (int i = 0; i < 8; i++) {
      int g = bid * 2048 + i * 256 + threadIdx.x;
      float4 v = X[g];
      ushort4 o;
      o.x = f2bf(v.x); o.y = f2bf(v.y); o.z = f2bf(v.z); o.w = f2bf(v.w);
      Xb[g] = o;
    }
    return;
  }
  bid -= 512;
  __shared__ __align__(16) u16 tb[64 * 68];
  const int col = threadIdx.x & 63;
  const int rowo = threadIdx.x >> 6;
#pragma unroll 1
  for (int t2 = 0; t2 < 2; t2++) {
    const int tile = bid * 2 + t2;
    const int z = tile >> 8, t = tile & 255;
    const float* W = (z == 0) ? w0 : (z == 1) ? w1 : (z == 2) ? w2 : w3;
    u16* O = out + z * 1048576;
    const int n0 = (t & 15) * 64, k0 = (t >> 4) * 64;
#pragma unroll
    for (int r = 0; r < 16; r++) {
      int kl = r * 4 + rowo;
      tb[col * 68 + kl] = f2bf(W[(k0 + kl) * 1024 + n0 + col]);
    }
    __syncthreads();
#pragma unroll
    for (int r = 0; r < 16; r++) {
      int nl = r * 4 + rowo;
      O[(n0 + nl) * 1024 + k0 + col] = tb[nl * 68 + col];
    }
    __syncthreads();
  }
}

// -------- QKV GEMM: 128x128 tiles, BK=32, async-LDS double buffer, raw barriers --------
// Pipeline: issue gld16 for tile k+1, then "s_waitcnt vmcnt(4); s_barrier" (waits only
// tile k's loads — k+1's stay in flight a full iteration). NO vmcnt(0) drain in the loop.
// No prefetch VGPRs (R5/R6 lesson: reg-prefetch spills next to 64 acc AGPRs).
__global__ __launch_bounds__(256) void gemm128(const u16* __restrict__ A,
                                               const u16* __restrict__ BtBase,
                                               u16* __restrict__ outp) {
  __shared__ __align__(16) u16 smem[18432];   // loop: 2 stages x 8192 u16; epilogue: retile
  const int tid = threadIdx.x, lane = tid & 63, wave = tid >> 6;
  const int l15 = lane & 15, quad = lane >> 4;
  const int wm = (wave >> 1) * 64, wn = (wave & 1) * 64;

  const int id = blockIdx.x + blockIdx.y * 24;
  const int xcd = id & 7, jj = id >> 3;
  const int nz = (jj % 12) + (xcd & 1) * 12;
  const int ymb = (jj / 12) + (xcd >> 1) * 8;
  const int n = nz / 3, z = nz % 3;
  const int m0 = ymb * 128, n0 = n * 128;
  const u16* Ab = A + m0 * 1024;
  const u16* Bb = BtBase + z * 1048576 + n0 * 1024;

  // staging coords: tile = 128 rows x 32 k; 16B chunk j holds src chunk j^((row>>1)&3)
  int cc0 = tid, cc1 = 256 + tid;
  int row0 = cc0 >> 2, row1 = cc1 >> 2;
  int aoff0 = row0 * 1024 + (((cc0 & 3) ^ ((row0 >> 1) & 3)) * 8);
  int aoff1 = row1 * 1024 + (((cc1 & 3) ^ ((row1 >> 1) & 3)) * 8);

  f32x4 acc[4][4];
  const f32x4 vz = {0.f, 0.f, 0.f, 0.f};
#pragma unroll
  for (int i = 0; i < 4; i++)
#pragma unroll
    for (int j = 0; j < 4; j++) acc[i][j] = vz;

  const int sk = (l15 >> 1) & 3;   // read-side swizzle key (2-way conflicts = free)

  // prologue: stage tile 0 into stage 0
  {
    u16* st = smem;
    gld16(st + cc0 * 8, Ab + aoff0);
    gld16(st + cc1 * 8, Ab + aoff1);
    gld16(st + 4096 + cc0 * 8, Bb + aoff0);
    gld16(st + 4096 + cc1 * 8, Bb + aoff1);
  }

#pragma unroll 1
  for (int kt = 0; kt < 32; kt++) {
    u16* st = smem + (kt & 1) * 8192;
    if (kt < 31) {
      u16* dst = smem + ((kt + 1) & 1) * 8192;
      const int ka = (kt + 1) * 32;
      gld16(dst + cc0 * 8, Ab + ka + aoff0);
      gld16(dst + cc1 * 8, Ab + ka + aoff1);
      gld16(dst + 4096 + cc0 * 8, Bb + ka + aoff0);
      gld16(dst + 4096 + cc1 * 8, Bb + ka + aoff1);
      asm volatile("s_waitcnt vmcnt(4)\n\ts_barrier" ::: "memory");
    } else {
      asm volatile("s_waitcnt vmcnt(0)\n\ts_barrier" ::: "memory");
    }
    bf16x8 af[4], bg[4];
#pragma unroll
    for (int mt = 0; mt < 4; mt++)
      af[mt] = *(const bf16x8*)(st + (wm + mt * 16 + l15) * 32 + ((quad ^ sk) * 8));
#pragma unroll
    for (int nt = 0; nt < 4; nt++)
      bg[nt] = *(const bf16x8*)(st + 4096 + (wn + nt * 16 + l15) * 32 + ((quad ^ sk) * 8));
#pragma unroll
    for (int mt = 0; mt < 4; mt++)
#pragma unroll
      for (int nt = 0; nt < 4; nt++)
        acc[mt][nt] = MFMA16(af[mt], bg[nt], acc[mt][nt]);
    asm volatile("s_barrier" ::: "memory");   // all reads of buffer done before its reuse
  }
  __syncthreads();   // full drain once before smem reuse in epilogue

  if (z == 2) {
    // transpose in LDS (col-major stride 136) then 16B coalesced stores to Vt[b,h,dk,s]
    u16* O = outp + z * 4194304;
#pragma unroll
    for (int mt = 0; mt < 4; mt++)
#pragma unroll
      for (int nt = 0; nt < 4; nt++) {
        int col = wn + nt * 16 + l15;
        int rowb = wm + mt * 16 + quad * 4;
        uint2 p;
        p.x = (u32)f2bf(acc[mt][nt][0]) | ((u32)f2bf(acc[mt][nt][1]) << 16);
        p.y = (u32)f2bf(acc[mt][nt][2]) | ((u32)f2bf(acc[mt][nt][3]) << 16);
        *(uint2*)(smem + col * 136 + rowb) = p;
      }
    __syncthreads();
    const int b = m0 >> 10, sbase = m0 & 1023;
#pragma unroll
    for (int p = 0; p < 8; p++) {
      int g = p * 256 + tid;
      int col = g >> 4, chunk = g & 15;
      uint4 v = *(const uint4*)(smem + col * 136 + chunk * 8);
      int nn = n0 + col, hh = nn >> 6, dk = nn & 63;
      *(uint4*)(O + ((b * 16 + hh) * 64 + dk) * 1024 + sbase + chunk * 8) = v;
    }
  } else {
    // retile [m][n] in LDS (stride 144) then 16B stores
    u16* O = outp + z * 4194304;
    const float scl = (z == 0) ? LOG2E : 1.0f;   // pre-scale Q for exp2-softmax
#pragma unroll
    for (int mt = 0; mt < 4; mt++)
#pragma unroll
      for (int nt = 0; nt < 4; nt++) {
        int rowb = wm + mt * 16 + quad * 4;
        int colb = wn + nt * 16 + l15;
#pragma unroll
        for (int reg = 0; reg < 4; reg++)
          smem[(rowb + reg) * 144 + colb] = f2bf(acc[mt][nt][reg] * scl);
      }
    __syncthreads();
    const int b = m0 >> 10, sbase = m0 & 1023;
#pragma unroll
    for (int p = 0; p < 8; p++) {
      int g = p * 256 + tid;
      int ml = g >> 4, c = g & 15;
      uint4 v = *(const uint4*)(smem + ml * 144 + c * 8);
      int nn = n0 + c * 8, hh = nn >> 6, dk = nn & 63;
      *(uint4*)(O + (b * 16 + hh) * 65536 + (sbase + ml) * 64 + dk) = v;
    }
  }
}

// ---------------- flash attention: block = (b,h) x 128 q-rows; wave = 32q x 64keys ----------------
__global__ __launch_bounds__(256) void attn(const u16* __restrict__ Q, const u16* __restrict__ K,
                                            const u16* __restrict__ V, const float* __restrict__ emb,
                                            u16* __restrict__ ctx) {
  __shared__ __align__(16) u16 sK[64 * 64];
  __shared__ __align__(16) u16 sV[64 * 64];     // V^T tile [d][s_local]
  __shared__ __align__(16) u16 sP[128 * 72];    // P [qrow][key], stride 72
  __shared__ __align__(16) float4 bt4[1156];    // replicated bias*log2e
  const int tid = threadIdx.x, lane = tid & 63, wave = tid >> 6;
  const int l15 = lane & 15, quad = lane >> 4;
  const int bh = blockIdx.x, qt = blockIdx.y;
  const int h = bh & 15, b = bh >> 4;
  const u16* Qp = Q + bh * 65536 + qt * 8192;
  const u16* Kp = K + bh * 65536;
  const u16* Vp = V + bh * 65536;
  const int sx = l15 & 7;

  bf16x8 aq[2][2];
#pragma unroll
  for (int u = 0; u < 2; u++)
#pragma unroll
    for (int kk = 0; kk < 2; kk++)
      aq[u][kk] = *(const bf16x8*)(Qp + (wave * 32 + u * 16 + l15) * 64 + kk * 32 + quad * 8);

  for (int i = tid; i < 1156; i += 256) {
    int rp0 = i - 127 - qt * 128;
    float4 v;
    v.x = emb[t5_bucket(rp0)     * 16 + h] * LOG2E;
    v.y = emb[t5_bucket(rp0 + 1) * 16 + h] * LOG2E;
    v.z = emb[t5_bucket(rp0 + 2) * 16 + h] * LOG2E;
    v.w = emb[t5_bucket(rp0 + 3) * 16 + h] * LOG2E;
    bt4[i] = v;
  }
  const float bias_pos = emb[31 * 16 + h] * LOG2E;  // rp >= 91
  const float bias_neg = emb[15 * 16 + h] * LOG2E;  // rp <= -91

  float2 ls2[2] = {{0.f, 0.f}, {0.f, 0.f}};
  f32x4 oc[2][4];
  const f32x4 vzero = {0.f, 0.f, 0.f, 0.f};
#pragma unroll
  for (int u = 0; u < 2; u++)
#pragma unroll
    for (int nt = 0; nt < 4; nt++) oc[u][nt] = vzero;

  __syncthreads();   // bt4 ready

#pragma unroll 1
  for (int j = 0; j < 16; j++) {
    const u16* Kj = Kp + j * 4096;
#pragma unroll
    for (int r = 0; r < 2; r++) {
      int cb = r * 256 + wave * 64;
      int cc = cb + lane;
      int row = cc >> 3, c8 = (cc & 7) ^ (row & 7);
      gld16(sK + cb * 8, Kj + row * 64 + c8 * 8);
      gld16(sV + cb * 8, Vp + row * 1024 + j * 64 + c8 * 8);
    }
    __syncthreads();

    // S^T = K.Q^T + bias  (lane: key = mt*16+quad*4+reg, qrow = u*16+l15)
    f32x4 sc[4][2];
    const int rp_min = j * 64 - qt * 128 - 127;
    const int rp_max = j * 64 + 63 - qt * 128;
    if (rp_min >= 91) {
#pragma unroll
      for (int mt = 0; mt < 4; mt++)
#pragma unroll
        for (int u = 0; u < 2; u++) { sc[mt][u][0] = bias_pos; sc[mt][u][1] = bias_pos; sc[mt][u][2] = bias_pos; sc[mt][u][3] = bias_pos; }
    } else if (rp_max <= -91) {
#pragma unroll
      for (int mt = 0; mt < 4; mt++)
#pragma unroll
        for (int u = 0; u < 2; u++) { sc[mt][u][0] = bias_neg; sc[mt][u][1] = bias_neg; sc[mt][u][2] = bias_neg; sc[mt][u][3] = bias_neg; }
    } else {
#pragma unroll
      for (int mt = 0; mt < 4; mt++)
#pragma unroll
        for (int u = 0; u < 2; u++) {
          int idx = j * 64 + mt * 16 + quad * 4 - wave * 32 - u * 16 - l15 + 127;
          float4 bv4 = bt4[idx];
          sc[mt][u][0] = bv4.x; sc[mt][u][1] = bv4.y; sc[mt][u][2] = bv4.z; sc[mt][u][3] = bv4.w;
        }
    }
#pragma unroll
    for (int kk = 0; kk < 2; kk++) {
      bf16x8 ak[4];
      int g8 = kk * 4 + quad;
#pragma unroll
      for (int mt = 0; mt < 4; mt++)
        ak[mt] = *(const bf16x8*)(sK + (mt * 16 + l15) * 64 + (g8 ^ sx) * 8);
#pragma unroll
      for (int mt = 0; mt < 4; mt++)
#pragma unroll
        for (int u = 0; u < 2; u++)
          sc[mt][u] = MFMA16(ak[mt], aq[u][kk], sc[mt][u]);
    }

    // softmax: truncate-to-bf16 P; lsum accumulated from truncated values
#pragma unroll
    for (int u = 0; u < 2; u++) {
      const int prow = wave * 32 + u * 16 + l15;
#pragma unroll
      for (int mt = 0; mt < 4; mt++) {
        u32 b0 = __float_as_uint(__builtin_amdgcn_exp2f(sc[mt][u][0]));
        u32 b1 = __float_as_uint(__builtin_amdgcn_exp2f(sc[mt][u][1]));
        u32 b2 = __float_as_uint(__builtin_amdgcn_exp2f(sc[mt][u][2]));
        u32 b3 = __float_as_uint(__builtin_amdgcn_exp2f(sc[mt][u][3]));
        u32 t0 = b0 & 0xFFFF0000u, t1 = b1 & 0xFFFF0000u;
        u32 t2 = b2 & 0xFFFF0000u, t3 = b3 & 0xFFFF0000u;
        ls2[u].x += __uint_as_float(t0) + __uint_as_float(t2);
        ls2[u].y += __uint_as_float(t1) + __uint_as_float(t3);
        uint2 pk;
        pk.x = (t0 >> 16) | t1;
        pk.y = (t2 >> 16) | t3;
        *(uint2*)(sP + prow * 72 + mt * 16 + quad * 4) = pk;
      }
    }
    asm volatile("s_waitcnt lgkmcnt(0)" ::: "memory");   // wave-private P write->read

    // O += P.V
#pragma unroll
    for (int kk = 0; kk < 2; kk++) {
      bf16x8 ap[2];
      int g8 = kk * 4 + quad;
#pragma unroll
      for (int u = 0; u < 2; u++)
        ap[u] = *(const bf16x8*)(sP + (wave * 32 + u * 16 + l15) * 72 + kk * 32 + quad * 8);
#pragma unroll
      for (int nt = 0; nt < 4; nt++) {
        bf16x8 bv = *(const bf16x8*)(sV + (nt * 16 + l15) * 64 + (g8 ^ sx) * 8);
#pragma unroll
        for (int u = 0; u < 2; u++)
          oc[u][nt] = MFMA16(ap[u], bv, oc[u][nt]);
      }
    }
    __syncthreads();
  }

  float lsum[2];
#pragma unroll
  for (int u = 0; u < 2; u++) {
    lsum[u] = ls2[u].x + ls2[u].y;
    lsum[u] += __shfl_xor(lsum[u], 16, 64);
    lsum[u] += __shfl_xor(lsum[u], 32, 64);
  }
  float linv[2][4];
#pragma unroll
  for (int u = 0; u < 2; u++)
#pragma unroll
    for (int reg = 0; reg < 4; reg++)
      linv[u][reg] = __builtin_amdgcn_rcpf(__shfl(lsum[u], quad * 4 + reg, 64));

  u16* cb2 = ctx + b * 1048576 + (qt * 128 + wave * 32) * 1024 + h * 64;
#pragma unroll
  for (int u = 0; u < 2; u++)
#pragma unroll
    for (int nt = 0; nt < 4; nt++)
#pragma unroll
      for (int reg = 0; reg < 4; reg++)
        cb2[(u * 16 + quad * 4 + reg) * 1024 + nt * 16 + l15] = f2bf(oc[u][nt][reg] * linv[u][reg]);
}

// -------- out-proj GEMM: 64m x 128n tiles, grid 512 (2 blocks/CU), async pipeline --------
__global__ __launch_bounds__(256) void gemm_o(const u16* __restrict__ A,
                                              const u16* __restrict__ Bt,
                                              float* __restrict__ O) {
  __shared__ __align__(16) u16 smem[24576];   // 2 stages x (A 64x64 + B 128x64) = 48 KB
  const int tid = threadIdx.x, lane = tid & 63, wave = tid >> 6;
  const int l15 = lane & 15, quad = lane >> 4;
  const int m0 = blockIdx.x * 64, n0 = blockIdx.y * 128;   // x=m -> XCD spread; B 2MB L2-resident
  const u16* Ab = A + m0 * 1024;
  const u16* Bb = Bt + n0 * 1024;
  const int wn = wave * 32;

  // staging: A rows 0..63 (2 chunks... cc 0..511 covers 64x64), B rows 0..127 (cc 0..1023)
  int ac = tid, bc0 = tid, bc1 = 256 + tid, bc2 = 512 + tid, bc3 = 768 + tid;
  // A: 64 rows x 64k: cc 0..511 -> row=cc>>3, c8=(cc&7)^(row&7)
  int ar0 = tid >> 3, ar1 = (256 + tid) >> 3;
  int aoff0 = ar0 * 1024 + (((tid & 7) ^ (ar0 & 7)) * 8);
  int aoff1 = ar1 * 1024 + ((((256 + tid) & 7) ^ (ar1 & 7)) * 8);
  int boff[4], bdst[4];
#pragma unroll
  for (int r = 0; r < 4; r++) {
    int cc = r * 256 + tid;
    int row = cc >> 3;
    boff[r] = row * 1024 + (((cc & 7) ^ (row & 7)) * 8);
    bdst[r] = cc * 8;
  }

  f32x4 acc[4][2];
  const f32x4 vz = {0.f, 0.f, 0.f, 0.f};
#pragma unroll
  for (int i = 0; i < 4; i++) { acc[i][0] = vz; acc[i][1] = vz; }

  const int sx = l15 & 7;

  {
    u16* st = smem;
    gld16(st + tid * 8, Ab + aoff0);
    gld16(st + (256 + tid) * 8, Ab + aoff1);
#pragma unroll
    for (int r = 0; r < 4; r++) gld16(st + 4096 + bdst[r], Bb + boff[r]);
  }

#pragma unroll 1
  for (int kt = 0; kt < 16; kt++) {
    u16* st = smem + (kt & 1) * 12288;
    if (kt < 15) {
      u16* dst = smem + ((kt + 1) & 1) * 12288;
      const int ka = (kt + 1) * 64;
      gld16(dst + tid * 8, Ab + ka + aoff0);
      gld16(dst + (256 + tid) * 8, Ab + ka + aoff1);
#pragma unroll
      for (int r = 0; r < 4; r++) gld16(dst + 4096 + bdst[r], Bb + ka + boff[r]);
      asm volatile("s_waitcnt vmcnt(6)\n\ts_barrier" ::: "memory");
    } else {
      asm volatile("s_waitcnt vmcnt(0)\n\ts_barrier" ::: "memory");
    }
#pragma unroll
    for (int kk = 0; kk < 2; kk++) {
      bf16x8 af[4], bg[2];
      int g8 = kk * 4 + quad;
#pragma unroll
      for (int mt = 0; mt < 4; mt++)
        af[mt] = *(const bf16x8*)(st + (mt * 16 + l15) * 64 + ((g8 ^ sx) * 8));
#pragma unroll
      for (int nt = 0; nt < 2; nt++)
        bg[nt] = *(const bf16x8*)(st + 4096 + (wn + nt * 16 + l15) * 64 + ((g8 ^ sx) * 8));
#pragma unroll
      for (int mt = 0; mt < 4; mt++)
#pragma unroll
        for (int nt = 0; nt < 2; nt++)
          acc[mt][nt] = MFMA16(af[mt], bg[nt], acc[mt][nt]);
    }
    asm volatile("s_barrier" ::: "memory");
  }

#pragma unroll
  for (int mt = 0; mt < 4; mt++)
#pragma unroll
    for (int nt = 0; nt < 2; nt++)
#pragma unroll
      for (int reg = 0; reg < 4; reg++) {
        int row = m0 + mt * 16 + quad * 4 + reg;
        int col = n0 + wn + nt * 16 + l15;
        O[row * 1024 + col] = acc[mt][nt][reg];
      }
}

extern "C" void kernel_launch(void* const* d_in, const int* in_sizes, int n_in,
                              void* d_out, int out_size, void* d_ws, size_t ws_size,
                              hipStream_t stream) {
  (void)in_sizes; (void)n_in; (void)out_size; (void)ws_size;
  const float* X   = (const float*)d_in[0];
  const float* Wq  = (const float*)d_in[1];
  const float* Wk  = (const float*)d_in[2];
  const float* Wv  = (const float*)d_in[3];
  const float* Wo  = (const float*)d_in[4];
  const float* emb = (const float*)d_in[5];

  char* ws = (char*)d_ws;
  u16* Xb  = (u16*)(ws);                              // 8 MB: X bf16 [4096][1024]
  u16* Wt  = (u16*)(ws + (8u  << 20));                // 8 MB: Wq^T,Wk^T,Wv^T,Wo^T bf16
  u16* Qb  = (u16*)(ws + (16u << 20));                // 8+8+8 MB: Q(log2e-scaled), K, Vt
  u16* Ctx = (u16*)(ws + (40u << 20));                // 8 MB: attention output bf16

  prep<<<1024, 256, 0, stream>>>((const float4*)X, (ushort4*)Xb, Wq, Wk, Wv, Wo, Wt);
  gemm128<<<dim3(24, 32), 256, 0, stream>>>(Xb, Wt, Qb);
  attn<<<dim3(64, 8), 256, 0, stream>>>(Qb, Qb + 4194304, Qb + 2 * 4194304, emb, Ctx);
  gemm_o<<<dim3(64, 8), 256, 0, stream>>>(Ctx, Wt + 3 * 1048576, (float*)d_out);
}

// Round 8
// 164.050 us; speedup vs baseline: 1.7888x; 1.0045x over previous
//
#include <hip/hip_runtime.h>

typedef unsigned short u16;
typedef unsigned int u32;
typedef __bf16 bf16x8 __attribute__((ext_vector_type(8)));
typedef float f32x4 __attribute__((ext_vector_type(4)));

#define MFMA16(a, b, c) __builtin_amdgcn_mfma_f32_16x16x32_bf16(a, b, c, 0, 0, 0)
#define LOG2E 1.4426950408889634f

__device__ __forceinline__ u16 f2bf(float f) {
  u32 u = __float_as_uint(f);
  u += 0x7FFFu + ((u >> 16) & 1u);   // RNE to bf16
  return (u16)(u >> 16);
}

__device__ __forceinline__ void gld16(u16* lds, const u16* g) {
  __builtin_amdgcn_global_load_lds((const __attribute__((address_space(1))) void*)g,
                                   (__attribute__((address_space(3))) void*)lds,
                                   16, 0, 0);
}

// Exact integer replication of T5 bucketing (bidirectional, 32 buckets, max_dist 128).
__device__ __forceinline__ int t5_bucket(int rp) {
  int ret = rp > 0 ? 16 : 0;
  int a = rp < 0 ? -rp : rp;
  int b;
  if      (a <  8) b = a;
  else if (a < 12) b = 8;
  else if (a < 16) b = 9;
  else if (a < 23) b = 10;
  else if (a < 32) b = 11;
  else if (a < 46) b = 12;
  else if (a < 64) b = 13;
  else if (a < 91) b = 14;
  else             b = 15;
  return ret + b;
}

// ---------------- fused prep, grid 1024: blocks 0..511 X cvt, 512..1023 W cvt ----
__global__ __launch_bounds__(256) void prep(const float4* __restrict__ X, ushort4* __restrict__ Xb,
                                            const float* __restrict__ w0, const float* __restrict__ w1,
                                            const float* __restrict__ w2, const float* __restrict__ w3,
                                            u16* __restrict__ out) {
  int bid = blockIdx.x;
  if (bid < 512) {
#pragma unroll
    for (int i = 0; i < 8; i++) {
      int g = bid * 2048 + i * 256 + threadIdx.x;
      float4 v = X[g];
      ushort4 o;
      o.x = f2bf(v.x); o.y = f2bf(v.y); o.z = f2bf(v.z); o.w = f2bf(v.w);
      Xb[g] = o;
    }
    return;
  }
  bid -= 512;
  __shared__ __align__(16) u16 tb[64 * 68];
  const int col = threadIdx.x & 63;
  const int rowo = threadIdx.x >> 6;
#pragma unroll 1
  for (int t2 = 0; t2 < 2; t2++) {
    const int tile = bid * 2 + t2;
    const int z = tile >> 8, t = tile & 255;
    const float* W = (z == 0) ? w0 : (z == 1) ? w1 : (z == 2) ? w2 : w3;
    u16* O = out + z * 1048576;
    const int n0 = (t & 15) * 64, k0 = (t >> 4) * 64;
#pragma unroll
    for (int r = 0; r < 16; r++) {
      int kl = r * 4 + rowo;
      tb[col * 68 + kl] = f2bf(W[(k0 + kl) * 1024 + n0 + col]);
    }
    __syncthreads();
#pragma unroll
    for (int r = 0; r < 16; r++) {
      int nl = r * 4 + rowo;
      O[(n0 + nl) * 1024 + k0 + col] = tb[nl * 68 + col];
    }
    __syncthreads();
  }
}

// -------- QKV GEMM: 128x128 tiles, BK=32, 3-stage async-LDS pipeline, raw barriers --------
// Depth-2 prefetch: tile k's loads issued at iter k-2, waited via vmcnt(8) at iter k
// (~2 compute phases of flight). Never vmcnt(0) in steady state.
__global__ __launch_bounds__(256) void gemm128(const u16* __restrict__ A,
                                               const u16* __restrict__ BtBase,
                                               u16* __restrict__ outp) {
  __shared__ __align__(16) u16 smem[24576];   // 3 stages x 8192 u16; epilogue retile reuses
  const int tid = threadIdx.x, lane = tid & 63, wave = tid >> 6;
  const int l15 = lane & 15, quad = lane >> 4;
  const int wm = (wave >> 1) * 64, wn = (wave & 1) * 64;

  const int id = blockIdx.x + blockIdx.y * 24;
  const int xcd = id & 7, jj = id >> 3;
  const int nz = (jj % 12) + (xcd & 1) * 12;
  const int ymb = (jj / 12) + (xcd >> 1) * 8;
  const int n = nz / 3, z = nz % 3;
  const int m0 = ymb * 128, n0 = n * 128;
  const u16* Ab = A + m0 * 1024;
  const u16* Bb = BtBase + z * 1048576 + n0 * 1024;

  // staging coords: tile = 128 rows x 32 k; 16B chunk j holds src chunk j^((row>>1)&3)
  int cc0 = tid, cc1 = 256 + tid;
  int row0 = cc0 >> 2, row1 = cc1 >> 2;
  int aoff0 = row0 * 1024 + (((cc0 & 3) ^ ((row0 >> 1) & 3)) * 8);
  int aoff1 = row1 * 1024 + (((cc1 & 3) ^ ((row1 >> 1) & 3)) * 8);

  f32x4 acc[4][4];
  const f32x4 vz = {0.f, 0.f, 0.f, 0.f};
#pragma unroll
  for (int i = 0; i < 4; i++)
#pragma unroll
    for (int j = 0; j < 4; j++) acc[i][j] = vz;

  const int sk = (l15 >> 1) & 3;   // read-side swizzle key (2-way conflicts = free)

  // prologue: tiles 0,1 into stages 0,1
  {
    gld16(smem + cc0 * 8, Ab + aoff0);
    gld16(smem + cc1 * 8, Ab + aoff1);
    gld16(smem + 4096 + cc0 * 8, Bb + aoff0);
    gld16(smem + 4096 + cc1 * 8, Bb + aoff1);
    gld16(smem + 8192 + cc0 * 8, Ab + 32 + aoff0);
    gld16(smem + 8192 + cc1 * 8, Ab + 32 + aoff1);
    gld16(smem + 12288 + cc0 * 8, Bb + 32 + aoff0);
    gld16(smem + 12288 + cc1 * 8, Bb + 32 + aoff1);
  }

  int cs = 0, ls = 2;
#pragma unroll 1
  for (int kt = 0; kt < 32; kt++) {
    if (kt < 30) {
      u16* dst = smem + ls * 8192;
      const int ka = (kt + 2) * 32;
      gld16(dst + cc0 * 8, Ab + ka + aoff0);
      gld16(dst + cc1 * 8, Ab + ka + aoff1);
      gld16(dst + 4096 + cc0 * 8, Bb + ka + aoff0);
      gld16(dst + 4096 + cc1 * 8, Bb + ka + aoff1);
      asm volatile("s_waitcnt vmcnt(8)\n\ts_barrier" ::: "memory");
    } else if (kt == 30) {
      asm volatile("s_waitcnt vmcnt(4)\n\ts_barrier" ::: "memory");
    } else {
      asm volatile("s_waitcnt vmcnt(0)\n\ts_barrier" ::: "memory");
    }
    u16* st = smem + cs * 8192;
    bf16x8 af[4], bg[4];
#pragma unroll
    for (int mt = 0; mt < 4; mt++)
      af[mt] = *(const bf16x8*)(st + (wm + mt * 16 + l15) * 32 + ((quad ^ sk) * 8));
#pragma unroll
    for (int nt = 0; nt < 4; nt++)
      bg[nt] = *(const bf16x8*)(st + 4096 + (wn + nt * 16 + l15) * 32 + ((quad ^ sk) * 8));
#pragma unroll
    for (int mt = 0; mt < 4; mt++)
#pragma unroll
      for (int nt = 0; nt < 4; nt++)
        acc[mt][nt] = MFMA16(af[mt], bg[nt], acc[mt][nt]);
    asm volatile("s_barrier" ::: "memory");   // all reads of cs-stage done before its reuse
    cs = (cs == 2) ? 0 : cs + 1;
    ls = (ls == 2) ? 0 : ls + 1;
  }
  __syncthreads();   // full drain once before smem reuse in epilogue

  if (z == 2) {
    // transpose in LDS (col-major stride 136) then 16B coalesced stores to Vt[b,h,dk,s]
    u16* O = outp + z * 4194304;
#pragma unroll
    for (int mt = 0; mt < 4; mt++)
#pragma unroll
      for (int nt = 0; nt < 4; nt++) {
        int col = wn + nt * 16 + l15;
        int rowb = wm + mt * 16 + quad * 4;
        uint2 p;
        p.x = (u32)f2bf(acc[mt][nt][0]) | ((u32)f2bf(acc[mt][nt][1]) << 16);
        p.y = (u32)f2bf(acc[mt][nt][2]) | ((u32)f2bf(acc[mt][nt][3]) << 16);
        *(uint2*)(smem + col * 136 + rowb) = p;
      }
    __syncthreads();
    const int b = m0 >> 10, sbase = m0 & 1023;
#pragma unroll
    for (int p = 0; p < 8; p++) {
      int g = p * 256 + tid;
      int col = g >> 4, chunk = g & 15;
      uint4 v = *(const uint4*)(smem + col * 136 + chunk * 8);
      int nn = n0 + col, hh = nn >> 6, dk = nn & 63;
      *(uint4*)(O + ((b * 16 + hh) * 64 + dk) * 1024 + sbase + chunk * 8) = v;
    }
  } else {
    // retile [m][n] in LDS (stride 144) then 16B stores
    u16* O = outp + z * 4194304;
    const float scl = (z == 0) ? LOG2E : 1.0f;   // pre-scale Q for exp2-softmax
#pragma unroll
    for (int mt = 0; mt < 4; mt++)
#pragma unroll
      for (int nt = 0; nt < 4; nt++) {
        int rowb = wm + mt * 16 + quad * 4;
        int colb = wn + nt * 16 + l15;
#pragma unroll
        for (int reg = 0; reg < 4; reg++)
          smem[(rowb + reg) * 144 + colb] = f2bf(acc[mt][nt][reg] * scl);
      }
    __syncthreads();
    const int b = m0 >> 10, sbase = m0 & 1023;
#pragma unroll
    for (int p = 0; p < 8; p++) {
      int g = p * 256 + tid;
      int ml = g >> 4, c = g & 15;
      uint4 v = *(const uint4*)(smem + ml * 144 + c * 8);
      int nn = n0 + c * 8, hh = nn >> 6, dk = nn & 63;
      *(uint4*)(O + (b * 16 + hh) * 65536 + (sbase + ml) * 64 + dk) = v;
    }
  }
}

// ------- flash attention: (b,h) x 128 q-rows; 2-stage K/V async double-buffer -------
__global__ __launch_bounds__(256) void attn(const u16* __restrict__ Q, const u16* __restrict__ K,
                                            const u16* __restrict__ V, const float* __restrict__ emb,
                                            u16* __restrict__ ctx) {
  __shared__ __align__(16) u16 sKV[2 * 8192];   // stage: sK(4096 u16) + sV(4096 u16)
  __shared__ __align__(16) u16 sP[128 * 72];    // P [qrow][key], stride 72
  __shared__ __align__(16) float4 bt4[1156];    // replicated bias*log2e
  const int tid = threadIdx.x, lane = tid & 63, wave = tid >> 6;
  const int l15 = lane & 15, quad = lane >> 4;
  const int bh = blockIdx.x, qt = blockIdx.y;
  const int h = bh & 15, b = bh >> 4;
  const u16* Qp = Q + bh * 65536 + qt * 8192;
  const u16* Kp = K + bh * 65536;
  const u16* Vp = V + bh * 65536;
  const int sx = l15 & 7;

  // staging coords (2 gld16 each for K and V per thread)
  int koff[2], voff[2], cbs[2];
#pragma unroll
  for (int r = 0; r < 2; r++) {
    int cb = r * 256 + wave * 64;
    int cc = cb + lane;
    int row = cc >> 3, c8 = (cc & 7) ^ (row & 7);
    koff[r] = row * 64 + c8 * 8;
    voff[r] = row * 1024 + c8 * 8;
    cbs[r] = cb * 8;
  }

  bf16x8 aq[2][2];
#pragma unroll
  for (int u = 0; u < 2; u++)
#pragma unroll
    for (int kk = 0; kk < 2; kk++)
      aq[u][kk] = *(const bf16x8*)(Qp + (wave * 32 + u * 16 + l15) * 64 + kk * 32 + quad * 8);

  // prologue: KV tile 0 into stage 0 (overlaps bias-table build)
#pragma unroll
  for (int r = 0; r < 2; r++) {
    gld16(sKV + cbs[r], Kp + koff[r]);
    gld16(sKV + 4096 + cbs[r], Vp + voff[r]);
  }

  for (int i = tid; i < 1156; i += 256) {
    int rp0 = i - 127 - qt * 128;
    float4 v;
    v.x = emb[t5_bucket(rp0)     * 16 + h] * LOG2E;
    v.y = emb[t5_bucket(rp0 + 1) * 16 + h] * LOG2E;
    v.z = emb[t5_bucket(rp0 + 2) * 16 + h] * LOG2E;
    v.w = emb[t5_bucket(rp0 + 3) * 16 + h] * LOG2E;
    bt4[i] = v;
  }
  const float bias_pos = emb[31 * 16 + h] * LOG2E;  // rp >= 91
  const float bias_neg = emb[15 * 16 + h] * LOG2E;  // rp <= -91

  float2 ls2[2] = {{0.f, 0.f}, {0.f, 0.f}};
  f32x4 oc[2][4];
  const f32x4 vzero = {0.f, 0.f, 0.f, 0.f};
#pragma unroll
  for (int u = 0; u < 2; u++)
#pragma unroll
    for (int nt = 0; nt < 4; nt++) oc[u][nt] = vzero;

  __syncthreads();   // bt4 ready (also drains tile-0 loads — startup only)

#pragma unroll 1
  for (int j = 0; j < 16; j++) {
    u16* st = sKV + (j & 1) * 8192;
    if (j < 15) {
      u16* dst = sKV + ((j + 1) & 1) * 8192;
      const u16* Kj1 = Kp + (j + 1) * 4096;
      const u16* Vj1 = Vp + (j + 1) * 64;
#pragma unroll
      for (int r = 0; r < 2; r++) {
        gld16(dst + cbs[r], Kj1 + koff[r]);
        gld16(dst + 4096 + cbs[r], Vj1 + voff[r]);
      }
      asm volatile("s_waitcnt vmcnt(4)\n\ts_barrier" ::: "memory");
    } else {
      asm volatile("s_waitcnt vmcnt(0)\n\ts_barrier" ::: "memory");
    }

    // S^T = K.Q^T + bias  (lane: key = mt*16+quad*4+reg, qrow = u*16+l15)
    f32x4 sc[4][2];
    const int rp_min = j * 64 - qt * 128 - 127;
    const int rp_max = j * 64 + 63 - qt * 128;
    if (rp_min >= 91) {
#pragma unroll
      for (int mt = 0; mt < 4; mt++)
#pragma unroll
        for (int u = 0; u < 2; u++) { sc[mt][u][0] = bias_pos; sc[mt][u][1] = bias_pos; sc[mt][u][2] = bias_pos; sc[mt][u][3] = bias_pos; }
    } else if (rp_max <= -91) {
#pragma unroll
      for (int mt = 0; mt < 4; mt++)
#pragma unroll
        for (int u = 0; u < 2; u++) { sc[mt][u][0] = bias_neg; sc[mt][u][1] = bias_neg; sc[mt][u][2] = bias_neg; sc[mt][u][3] = bias_neg; }
    } else {
#pragma unroll
      for (int mt = 0; mt < 4; mt++)
#pragma unroll
        for (int u = 0; u < 2; u++) {
          int idx = j * 64 + mt * 16 + quad * 4 - wave * 32 - u * 16 - l15 + 127;
          float4 bv4 = bt4[idx];
          sc[mt][u][0] = bv4.x; sc[mt][u][1] = bv4.y; sc[mt][u][2] = bv4.z; sc[mt][u][3] = bv4.w;
        }
    }
#pragma unroll
    for (int kk = 0; kk < 2; kk++) {
      bf16x8 ak[4];
      int g8 = kk * 4 + quad;
#pragma unroll
      for (int mt = 0; mt < 4; mt++)
        ak[mt] = *(const bf16x8*)(st + (mt * 16 + l15) * 64 + (g8 ^ sx) * 8);
#pragma unroll
      for (int mt = 0; mt < 4; mt++)
#pragma unroll
        for (int u = 0; u < 2; u++)
          sc[mt][u] = MFMA16(ak[mt], aq[u][kk], sc[mt][u]);
    }

    // softmax: truncate-to-bf16 P; lsum accumulated from truncated values
#pragma unroll
    for (int u = 0; u < 2; u++) {
      const int prow = wave * 32 + u * 16 + l15;
#pragma unroll
      for (int mt = 0; mt < 4; mt++) {
        u32 b0 = __float_as_uint(__builtin_amdgcn_exp2f(sc[mt][u][0]));
        u32 b1 = __float_as_uint(__builtin_amdgcn_exp2f(sc[mt][u][1]));
        u32 b2 = __float_as_uint(__builtin_amdgcn_exp2f(sc[mt][u][2]));
        u32 b3 = __float_as_uint(__builtin_amdgcn_exp2f(sc[mt][u][3]));
        u32 t0 = b0 & 0xFFFF0000u, t1 = b1 & 0xFFFF0000u;
        u32 t2 = b2 & 0xFFFF0000u, t3 = b3 & 0xFFFF0000u;
        ls2[u].x += __uint_as_float(t0) + __uint_as_float(t2);
        ls2[u].y += __uint_as_float(t1) + __uint_as_float(t3);
        uint2 pk;
        pk.x = (t0 >> 16) | t1;
        pk.y = (t2 >> 16) | t3;
        *(uint2*)(sP + prow * 72 + mt * 16 + quad * 4) = pk;
      }
    }
    asm volatile("s_waitcnt lgkmcnt(0)" ::: "memory");   // wave-private P write->read

    // O += P.V
#pragma unroll
    for (int kk = 0; kk < 2; kk++) {
      bf16x8 ap[2];
      int g8 = kk * 4 + quad;
#pragma unroll
      for (int u = 0; u < 2; u++)
        ap[u] = *(const bf16x8*)(sP + (wave * 32 + u * 16 + l15) * 72 + kk * 32 + quad * 8);
#pragma unroll
      for (int nt = 0; nt < 4; nt++) {
        bf16x8 bv = *(const bf16x8*)(st + 4096 + (nt * 16 + l15) * 64 + (g8 ^ sx) * 8);
#pragma unroll
        for (int u = 0; u < 2; u++)
          oc[u][nt] = MFMA16(ap[u], bv, oc[u][nt]);
      }
    }
    asm volatile("s_barrier" ::: "memory");   // stage reads done before its reuse
  }

  float lsum[2];
#pragma unroll
  for (int u = 0; u < 2; u++) {
    lsum[u] = ls2[u].x + ls2[u].y;
    lsum[u] += __shfl_xor(lsum[u], 16, 64);
    lsum[u] += __shfl_xor(lsum[u], 32, 64);
  }
  float linv[2][4];
#pragma unroll
  for (int u = 0; u < 2; u++)
#pragma unroll
    for (int reg = 0; reg < 4; reg++)
      linv[u][reg] = __builtin_amdgcn_rcpf(__shfl(lsum[u], quad * 4 + reg, 64));

  u16* cb2 = ctx + b * 1048576 + (qt * 128 + wave * 32) * 1024 + h * 64;
#pragma unroll
  for (int u = 0; u < 2; u++)
#pragma unroll
    for (int nt = 0; nt < 4; nt++)
#pragma unroll
      for (int reg = 0; reg < 4; reg++)
        cb2[(u * 16 + quad * 4 + reg) * 1024 + nt * 16 + l15] = f2bf(oc[u][nt][reg] * linv[u][reg]);
}

// -------- out-proj GEMM: 64m x 128n tiles, 3-stage async pipeline, fp32 out --------
__global__ __launch_bounds__(256) void gemm_o(const u16* __restrict__ A,
                                              const u16* __restrict__ Bt,
                                              float* __restrict__ O) {
  __shared__ __align__(16) u16 smem[36864];   // 3 stages x (A 4096 + B 8192) u16 = 72 KB
  const int tid = threadIdx.x, lane = tid & 63, wave = tid >> 6;
  const int l15 = lane & 15, quad = lane >> 4;
  const int m0 = blockIdx.x * 64, n0 = blockIdx.y * 128;
  const u16* Ab = A + m0 * 1024;
  const u16* Bb = Bt + n0 * 1024;
  const int wn = wave * 32;

  int ar0 = tid >> 3, ar1 = (256 + tid) >> 3;
  int aoff0 = ar0 * 1024 + (((tid & 7) ^ (ar0 & 7)) * 8);
  int aoff1 = ar1 * 1024 + ((((256 + tid) & 7) ^ (ar1 & 7)) * 8);
  int boff[4], bdst[4];
#pragma unroll
  for (int r = 0; r < 4; r++) {
    int cc = r * 256 + tid;
    int row = cc >> 3;
    boff[r] = row * 1024 + (((cc & 7) ^ (row & 7)) * 8);
    bdst[r] = cc * 8;
  }

  f32x4 acc[4][2];
  const f32x4 vz = {0.f, 0.f, 0.f, 0.f};
#pragma unroll
  for (int i = 0; i < 4; i++) { acc[i][0] = vz; acc[i][1] = vz; }

  const int sx = l15 & 7;

  // prologue: tiles 0,1 into stages 0,1
#pragma unroll
  for (int s = 0; s < 2; s++) {
    u16* st = smem + s * 12288;
    const int ka = s * 64;
    gld16(st + tid * 8, Ab + ka + aoff0);
    gld16(st + (256 + tid) * 8, Ab + ka + aoff1);
#pragma unroll
    for (int r = 0; r < 4; r++) gld16(st + 4096 + bdst[r], Bb + ka + boff[r]);
  }

  int cs = 0, ls = 2;
#pragma unroll 1
  for (int kt = 0; kt < 16; kt++) {
    if (kt < 14) {
      u16* dst = smem + ls * 12288;
      const int ka = (kt + 2) * 64;
      gld16(dst + tid * 8, Ab + ka + aoff0);
      gld16(dst + (256 + tid) * 8, Ab + ka + aoff1);
#pragma unroll
      for (int r = 0; r < 4; r++) gld16(dst + 4096 + bdst[r], Bb + ka + boff[r]);
      asm volatile("s_waitcnt vmcnt(12)\n\ts_barrier" ::: "memory");
    } else if (kt == 14) {
      asm volatile("s_waitcnt vmcnt(6)\n\ts_barrier" ::: "memory");
    } else {
      asm volatile("s_waitcnt vmcnt(0)\n\ts_barrier" ::: "memory");
    }
    u16* st = smem + cs * 12288;
#pragma unroll
    for (int kk = 0; kk < 2; kk++) {
      bf16x8 af[4], bg[2];
      int g8 = kk * 4 + quad;
#pragma unroll
      for (int mt = 0; mt < 4; mt++)
        af[mt] = *(const bf16x8*)(st + (mt * 16 + l15) * 64 + ((g8 ^ sx) * 8));
#pragma unroll
      for (int nt = 0; nt < 2; nt++)
        bg[nt] = *(const bf16x8*)(st + 4096 + (wn + nt * 16 + l15) * 64 + ((g8 ^ sx) * 8));
#pragma unroll
      for (int mt = 0; mt < 4; mt++)
#pragma unroll
        for (int nt = 0; nt < 2; nt++)
          acc[mt][nt] = MFMA16(af[mt], bg[nt], acc[mt][nt]);
    }
    asm volatile("s_barrier" ::: "memory");
    cs = (cs == 2) ? 0 : cs + 1;
    ls = (ls == 2) ? 0 : ls + 1;
  }

#pragma unroll
  for (int mt = 0; mt < 4; mt++)
#pragma unroll
    for (int nt = 0; nt < 2; nt++)
#pragma unroll
      for (int reg = 0; reg < 4; reg++) {
        int row = m0 + mt * 16 + quad * 4 + reg;
        int col = n0 + wn + nt * 16 + l15;
        O[row * 1024 + col] = acc[mt][nt][reg];
      }
}

extern "C" void kernel_launch(void* const* d_in, const int* in_sizes, int n_in,
                              void* d_out, int out_size, void* d_ws, size_t ws_size,
                              hipStream_t stream) {
  (void)in_sizes; (void)n_in; (void)out_size; (void)ws_size;
  const float* X   = (const float*)d_in[0];
  const float* Wq  = (const float*)d_in[1];
  const float* Wk  = (const float*)d_in[2];
  const float* Wv  = (const float*)d_in[3];
  const float* Wo  = (const float*)d_in[4];
  const float* emb = (const float*)d_in[5];

  char* ws = (char*)d_ws;
  u16* Xb  = (u16*)(ws);                              // 8 MB: X bf16 [4096][1024]
  u16* Wt  = (u16*)(ws + (8u  << 20));                // 8 MB: Wq^T,Wk^T,Wv^T,Wo^T bf16
  u16* Qb  = (u16*)(ws + (16u << 20));                // 8+8+8 MB: Q(log2e-scaled), K, Vt
  u16* Ctx = (u16*)(ws + (40u << 20));                // 8 MB: attention output bf16

  prep<<<1024, 256, 0, stream>>>((const float4*)X, (ushort4*)Xb, Wq, Wk, Wv, Wo, Wt);
  gemm128<<<dim3(24, 32), 256, 0, stream>>>(Xb, Wt, Qb);
  attn<<<dim3(64, 8), 256, 0, stream>>>(Qb, Qb + 4194304, Qb + 2 * 4194304, emb, Ctx);
  gemm_o<<<dim3(64, 8), 256, 0, stream>>>(Ctx, Wt + 3 * 1048576, (float*)d_out);
}